// Round 7
// baseline (613.696 us; speedup 1.0000x reference)
//
#include <hip/hip_runtime.h>
#include <hip/hip_bf16.h>

typedef short bf16x8 __attribute__((ext_vector_type(8)));
typedef float f32x4  __attribute__((ext_vector_type(4)));

#define H_NODE 64
#define H_EDGE 128
#define WAVES  8
#define BLOCK  512
#define GRID   256
#define LN_EPS 1e-5f

// Static LDS layout (byte offsets), 160 KiB exactly (1 block/CU):
//   [0,      65536): W1^T bf16: addr = col*512 + ((k*2) ^ ((col&7)<<4)),  col<128, k<256
//   [65536,  98304): W2^T bf16: addr = 65536 + col*256 + ((k*2) ^ ((col&7)<<4)), k<128
//   [98304, 163840): per-wave transpose tiles, 8KB/wave: half-A at +0, half-B at +4096
//                    (each 16 rows x 128 bf16, used for h then w, r3-verbatim swizzle)
//
// Round-7: PAIRED ROW-TILES. Each wave owns 32 edge rows (two 16-row halves A,B).
// All r3-proven data paths kept verbatim (operand order, h/w LDS transpose,
// register-resident residual, float4 store covering 128B/row/step, 8 waves x
// 256 VGPR, full 1-iteration-deep register staging of node+edge gathers).
// Change: loop nesting is weight-fragment-OUTER so each W1/W2 LDS fragment is
// read ONCE and consumed by TWO MFMAs (half A + half B):
//   - per-edge ds_read_b128 weight traffic halves (the dominant LDS-pipe term)
//   - each LDS read is covered by ~2 MFMAs of independent work (ILP)
// Register economy to fit 256: staging 128 (in flight across whole iteration),
// edge frags 32 (residual), acc 64 (shared GEMM1/GEMM2), node frags JIT-cvt
// per k-chunk (8 live), A2 frags JIT per t2 (8 live), LN consts reloaded per
// pair (L1-hot) instead of persistent.
// Spill tripwire: WRITE_SIZE > 600 MB -> revert to r3 champion next round.

static __device__ __forceinline__ short f2bf(float x) {
    __hip_bfloat16 h = __float2bfloat16(x);   // RNE
    return *reinterpret_cast<short*>(&h);
}

static __device__ __forceinline__ float bf2f(short s) {
    union { unsigned int u; float f; } v;
    v.u = ((unsigned int)(unsigned short)s) << 16;
    return v.f;
}

static __device__ __forceinline__ int tswz(int r, int g) {
    return r * 256 + ((g ^ ((r >> 2) << 1)) << 4);
}

static __device__ __forceinline__ bf16x8 cvt8(f32x4 lo, f32x4 hi) {
    bf16x8 f;
    f[0] = f2bf(lo[0]); f[1] = f2bf(lo[1]); f[2] = f2bf(lo[2]); f[3] = f2bf(lo[3]);
    f[4] = f2bf(hi[0]); f[5] = f2bf(hi[1]); f[6] = f2bf(hi[2]); f[7] = f2bf(hi[3]);
    return f;
}

extern "C" __global__ void __launch_bounds__(BLOCK, 2)
edge_update(const float* __restrict__ node,
            const float* __restrict__ edgef,
            const int* __restrict__ ei,          // int32 on device
            const float* __restrict__ W1, const float* __restrict__ b1,
            const float* __restrict__ W2, const float* __restrict__ b2,
            const float* __restrict__ gamma, const float* __restrict__ beta,
            float* __restrict__ out, int E)
{
    __shared__ char lds[163840];
    const int tid = threadIdx.x;

    // ---- stage W1^T (bf16, swizzled) ----
    for (int e = tid; e < 32768; e += BLOCK) {   // W1 is [k][n], k<256, n<128
        int k = e >> 7, n = e & 127;
        float v = W1[e];
        int addr = n * 512 + ((k * 2) ^ ((n & 7) << 4));
        *(short*)(lds + addr) = f2bf(v);
    }
    // ---- stage W2^T ----
    for (int e = tid; e < 16384; e += BLOCK) {   // W2 is [k][n], k<128, n<128
        int k = e >> 7, n = e & 127;
        float v = W2[e];
        int addr = 65536 + n * 256 + ((k * 2) ^ ((n & 7) << 4));
        *(short*)(lds + addr) = f2bf(v);
    }
    __syncthreads();

    const int wid   = tid >> 6;
    const int lane  = tid & 63;
    const int lrow  = lane & 15;   // A-frag row / C col / B col
    const int lk8   = lane >> 4;   // k-subchunk 0..3
    const int hbA   = 98304 + wid * 8192;
    const int hbB   = hbA + 4096;
    const int rsw   = (lrow & 7) << 4;   // weight-read swizzle (col&7 == lrow&7)

    const int nt32    = (E + 31) >> 5;
    const int wstride = GRID * WAVES;

    int t32 = blockIdx.x * WAVES + wid;
    if (t32 >= nt32) return;

    // ---- prologue: indices + staged gather for pair t32; indices for next ----
    int rA = t32 * 32 + lrow;      if (rA >= E) rA = E - 1;
    int rB = t32 * 32 + 16 + lrow; if (rB >= E) rB = E - 1;
    int sA = ei[rA], dA = ei[E + rA];
    int sB = ei[rB], dB = ei[E + rB];

    f32x4 SnA0, SnA1, SnA2, SnA3, SnA4, SnA5, SnA6, SnA7;
    f32x4 SnB0, SnB1, SnB2, SnB3, SnB4, SnB5, SnB6, SnB7;
    f32x4 SeA0, SeA1, SeA2, SeA3, SeA4, SeA5, SeA6, SeA7;
    f32x4 SeB0, SeB1, SeB2, SeB3, SeB4, SeB5, SeB6, SeB7;
    {
        const float* spA = node + (size_t)sA * H_NODE + lk8 * 8;
        const float* dpA = node + (size_t)dA * H_NODE + lk8 * 8;
        const float* epA = edgef + (size_t)rA * H_EDGE + lk8 * 8;
        const float* spB = node + (size_t)sB * H_NODE + lk8 * 8;
        const float* dpB = node + (size_t)dB * H_NODE + lk8 * 8;
        const float* epB = edgef + (size_t)rB * H_EDGE + lk8 * 8;
        SnA0 = *(const f32x4*)(spA);      SnA1 = *(const f32x4*)(spA + 4);
        SnA2 = *(const f32x4*)(spA + 32); SnA3 = *(const f32x4*)(spA + 36);
        SnA4 = *(const f32x4*)(dpA);      SnA5 = *(const f32x4*)(dpA + 4);
        SnA6 = *(const f32x4*)(dpA + 32); SnA7 = *(const f32x4*)(dpA + 36);
        SnB0 = *(const f32x4*)(spB);      SnB1 = *(const f32x4*)(spB + 4);
        SnB2 = *(const f32x4*)(spB + 32); SnB3 = *(const f32x4*)(spB + 36);
        SnB4 = *(const f32x4*)(dpB);      SnB5 = *(const f32x4*)(dpB + 4);
        SnB6 = *(const f32x4*)(dpB + 32); SnB7 = *(const f32x4*)(dpB + 36);
        SeA0 = *(const f32x4*)(epA);      SeA1 = *(const f32x4*)(epA + 4);
        SeA2 = *(const f32x4*)(epA + 32); SeA3 = *(const f32x4*)(epA + 36);
        SeA4 = *(const f32x4*)(epA + 64); SeA5 = *(const f32x4*)(epA + 68);
        SeA6 = *(const f32x4*)(epA + 96); SeA7 = *(const f32x4*)(epA + 100);
        SeB0 = *(const f32x4*)(epB);      SeB1 = *(const f32x4*)(epB + 4);
        SeB2 = *(const f32x4*)(epB + 32); SeB3 = *(const f32x4*)(epB + 36);
        SeB4 = *(const f32x4*)(epB + 64); SeB5 = *(const f32x4*)(epB + 68);
        SeB6 = *(const f32x4*)(epB + 96); SeB7 = *(const f32x4*)(epB + 100);
    }
    int nx  = t32 + wstride;
    int nrA = nx * 32 + lrow;      if (nrA >= E) nrA = E - 1;
    int nrB = nx * 32 + 16 + lrow; if (nrB >= E) nrB = E - 1;
    int nsA = ei[nrA], ndA = ei[E + nrA];
    int nsB = ei[nrB], ndB = ei[E + nrB];

    while (t32 < nt32) {
        // ---- cvt edge halves (frees Se*; EA/EB live till residual store) ----
        bf16x8 EA[4], EB[4];
        EA[0] = cvt8(SeA0, SeA1); EA[1] = cvt8(SeA2, SeA3);
        EA[2] = cvt8(SeA4, SeA5); EA[3] = cvt8(SeA6, SeA7);
        EB[0] = cvt8(SeB0, SeB1); EB[1] = cvt8(SeB2, SeB3);
        EB[2] = cvt8(SeB4, SeB5); EB[3] = cvt8(SeB6, SeB7);

        // ---- issue NEXT pair's EDGE loads (in flight ~whole iteration) ----
        {
            const float* epA = edgef + (size_t)nrA * H_EDGE + lk8 * 8;
            const float* epB = edgef + (size_t)nrB * H_EDGE + lk8 * 8;
            SeA0 = *(const f32x4*)(epA);      SeA1 = *(const f32x4*)(epA + 4);
            SeA2 = *(const f32x4*)(epA + 32); SeA3 = *(const f32x4*)(epA + 36);
            SeA4 = *(const f32x4*)(epA + 64); SeA5 = *(const f32x4*)(epA + 68);
            SeA6 = *(const f32x4*)(epA + 96); SeA7 = *(const f32x4*)(epA + 100);
            SeB0 = *(const f32x4*)(epB);      SeB1 = *(const f32x4*)(epB + 4);
            SeB2 = *(const f32x4*)(epB + 32); SeB3 = *(const f32x4*)(epB + 36);
            SeB4 = *(const f32x4*)(epB + 64); SeB5 = *(const f32x4*)(epB + 68);
            SeB6 = *(const f32x4*)(epB + 96); SeB7 = *(const f32x4*)(epB + 100);
        }

        // ---- GEMM1, k-chunks t=0..3 (node halves, JIT cvt from staging) ----
        f32x4 accA[8], accB[8];
        #pragma unroll
        for (int n = 0; n < 8; ++n) { accA[n] = (f32x4){0.f,0.f,0.f,0.f};
                                      accB[n] = (f32x4){0.f,0.f,0.f,0.f}; }
        {
            bf16x8 fa, fb;
            #pragma unroll
            for (int t = 0; t < 4; ++t) {
                switch (t) {
                    case 0: fa = cvt8(SnA0, SnA1); fb = cvt8(SnB0, SnB1); break;
                    case 1: fa = cvt8(SnA2, SnA3); fb = cvt8(SnB2, SnB3); break;
                    case 2: fa = cvt8(SnA4, SnA5); fb = cvt8(SnB4, SnB5); break;
                    default:fa = cvt8(SnA6, SnA7); fb = cvt8(SnB6, SnB7); break;
                }
                const int kb = t * 64 + lk8 * 16;
                #pragma unroll
                for (int n = 0; n < 8; ++n) {
                    bf16x8 bfrag = *(const bf16x8*)(lds + (n*16 + lrow)*512 + (kb ^ rsw));
                    accA[n] = __builtin_amdgcn_mfma_f32_16x16x32_bf16(fa, bfrag, accA[n], 0, 0, 0);
                    accB[n] = __builtin_amdgcn_mfma_f32_16x16x32_bf16(fb, bfrag, accB[n], 0, 0, 0);
                }
            }
        }

        // ---- node staging consumed: issue NEXT pair's NODE gathers ----
        {
            const float* spA = node + (size_t)nsA * H_NODE + lk8 * 8;
            const float* dpA = node + (size_t)ndA * H_NODE + lk8 * 8;
            const float* spB = node + (size_t)nsB * H_NODE + lk8 * 8;
            const float* dpB = node + (size_t)ndB * H_NODE + lk8 * 8;
            SnA0 = *(const f32x4*)(spA);      SnA1 = *(const f32x4*)(spA + 4);
            SnA2 = *(const f32x4*)(spA + 32); SnA3 = *(const f32x4*)(spA + 36);
            SnA4 = *(const f32x4*)(dpA);      SnA5 = *(const f32x4*)(dpA + 4);
            SnA6 = *(const f32x4*)(dpA + 32); SnA7 = *(const f32x4*)(dpA + 36);
            SnB0 = *(const f32x4*)(spB);      SnB1 = *(const f32x4*)(spB + 4);
            SnB2 = *(const f32x4*)(spB + 32); SnB3 = *(const f32x4*)(spB + 36);
            SnB4 = *(const f32x4*)(dpB);      SnB5 = *(const f32x4*)(dpB + 4);
            SnB6 = *(const f32x4*)(dpB + 32); SnB7 = *(const f32x4*)(dpB + 36);
        }
        // ---- prefetch pair+2 indices ----
        int nx2 = nx + wstride;
        int n2rA = nx2 * 32 + lrow;      if (n2rA >= E) n2rA = E - 1;
        int n2rB = nx2 * 32 + 16 + lrow; if (n2rB >= E) n2rB = E - 1;
        int n2sA = ei[n2rA], n2dA = ei[E + n2rA];
        int n2sB = ei[n2rB], n2dB = ei[E + n2rB];

        // ---- GEMM1, k-chunks t=4..7 (edge halves) ----
        #pragma unroll
        for (int t = 0; t < 4; ++t) {
            const int kb = (t + 4) * 64 + lk8 * 16;
            #pragma unroll
            for (int n = 0; n < 8; ++n) {
                bf16x8 bfrag = *(const bf16x8*)(lds + (n*16 + lrow)*512 + (kb ^ rsw));
                accA[n] = __builtin_amdgcn_mfma_f32_16x16x32_bf16(EA[t], bfrag, accA[n], 0, 0, 0);
                accB[n] = __builtin_amdgcn_mfma_f32_16x16x32_bf16(EB[t], bfrag, accB[n], 0, 0, 0);
            }
        }

        // ---- b1 reload (L1-hot) + bias+relu -> h to both per-wave tiles ----
        {
            float b1v[8];
            #pragma unroll
            for (int n = 0; n < 8; ++n) b1v[n] = b1[n * 16 + lrow];
            #pragma unroll
            for (int n = 0; n < 8; ++n) {
                const int g = n * 2 + (lrow >> 3);
                const int cl = (lrow & 7) * 2;
                #pragma unroll
                for (int i = 0; i < 4; ++i) {
                    int row = lk8 * 4 + i;
                    float uA = fmaxf(accA[n][i] + b1v[n], 0.f);
                    float uB = fmaxf(accB[n][i] + b1v[n], 0.f);
                    *(short*)(lds + hbA + tswz(row, g) + cl) = f2bf(uA);
                    *(short*)(lds + hbB + tswz(row, g) + cl) = f2bf(uB);
                }
            }
        }
        asm volatile("s_waitcnt lgkmcnt(0)" ::: "memory");

        // ---- GEMM2: t2-outer, shared W2 fragment across halves ----
        #pragma unroll
        for (int n = 0; n < 8; ++n) { accA[n] = (f32x4){0.f,0.f,0.f,0.f};
                                      accB[n] = (f32x4){0.f,0.f,0.f,0.f}; }
        #pragma unroll
        for (int t2 = 0; t2 < 4; ++t2) {
            bf16x8 A2a = *(const bf16x8*)(lds + hbA + tswz(lrow, t2 * 4 + lk8));
            bf16x8 A2b = *(const bf16x8*)(lds + hbB + tswz(lrow, t2 * 4 + lk8));
            const int kb = t2 * 64 + lk8 * 16;
            #pragma unroll
            for (int n = 0; n < 8; ++n) {
                bf16x8 bfrag = *(const bf16x8*)(lds + 65536 + (n*16 + lrow)*256 + (kb ^ rsw));
                accA[n] = __builtin_amdgcn_mfma_f32_16x16x32_bf16(A2a, bfrag, accA[n], 0, 0, 0);
                accB[n] = __builtin_amdgcn_mfma_f32_16x16x32_bf16(A2b, bfrag, accB[n], 0, 0, 0);
            }
        }

        // ---- LN consts reload (L1-hot, shared by both halves) ----
        float b2v[8], gv[8], btv[8];
        #pragma unroll
        for (int n = 0; n < 8; ++n) {
            int c = n * 16 + lrow;
            b2v[n] = b2[c]; gv[n] = gamma[c]; btv[n] = beta[c];
        }

        // ---- bias2 + LayerNorm half A -> w to tile A ----
        #pragma unroll
        for (int i = 0; i < 4; ++i) {
            float u[8];
            float s = 0.f, sq = 0.f;
            #pragma unroll
            for (int n = 0; n < 8; ++n) {
                u[n] = accA[n][i] + b2v[n];
                s += u[n]; sq += u[n] * u[n];
            }
            #pragma unroll
            for (int m = 1; m < 16; m <<= 1) {
                s  += __shfl_xor(s,  m, 64);
                sq += __shfl_xor(sq, m, 64);
            }
            float mu  = s * (1.f / 128.f);
            float var = sq * (1.f / 128.f) - mu * mu;
            float rs  = rsqrtf(var + LN_EPS);
            int row = lk8 * 4 + i;
            const int cl = (lrow & 7) * 2;
            #pragma unroll
            for (int n = 0; n < 8; ++n) {
                float w = (u[n] - mu) * rs * gv[n] + btv[n];
                *(short*)(lds + hbA + tswz(row, n * 2 + (lrow >> 3)) + cl) = f2bf(w);
            }
        }
        // ---- bias2 + LayerNorm half B -> w to tile B ----
        #pragma unroll
        for (int i = 0; i < 4; ++i) {
            float u[8];
            float s = 0.f, sq = 0.f;
            #pragma unroll
            for (int n = 0; n < 8; ++n) {
                u[n] = accB[n][i] + b2v[n];
                s += u[n]; sq += u[n] * u[n];
            }
            #pragma unroll
            for (int m = 1; m < 16; m <<= 1) {
                s  += __shfl_xor(s,  m, 64);
                sq += __shfl_xor(sq, m, 64);
            }
            float mu  = s * (1.f / 128.f);
            float var = sq * (1.f / 128.f) - mu * mu;
            float rs  = rsqrtf(var + LN_EPS);
            int row = lk8 * 4 + i;
            const int cl = (lrow & 7) * 2;
            #pragma unroll
            for (int n = 0; n < 8; ++n) {
                float w = (u[n] - mu) * rs * gv[n] + btv[n];
                *(short*)(lds + hbB + tswz(row, n * 2 + (lrow >> 3)) + cl) = f2bf(w);
            }
        }
        asm volatile("s_waitcnt lgkmcnt(0)" ::: "memory");

        // ---- stores: w in A-layout + register residual, r3-verbatim per half ----
        {
            int row = t32 * 32 + lrow;
            if (row < E) {
                float* orow = out + (size_t)row * H_EDGE;
                #pragma unroll
                for (int t = 0; t < 4; ++t) {
                    bf16x8 wf = *(const bf16x8*)(lds + hbA + tswz(lrow, t * 4 + lk8));
                    bf16x8 ef = EA[t];
                    float4 lo, hi;
                    lo.x = bf2f(wf[0]) + bf2f(ef[0]);
                    lo.y = bf2f(wf[1]) + bf2f(ef[1]);
                    lo.z = bf2f(wf[2]) + bf2f(ef[2]);
                    lo.w = bf2f(wf[3]) + bf2f(ef[3]);
                    hi.x = bf2f(wf[4]) + bf2f(ef[4]);
                    hi.y = bf2f(wf[5]) + bf2f(ef[5]);
                    hi.z = bf2f(wf[6]) + bf2f(ef[6]);
                    hi.w = bf2f(wf[7]) + bf2f(ef[7]);
                    float* dst = orow + t * 32 + lk8 * 8;
                    *(float4*)dst       = lo;
                    *(float4*)(dst + 4) = hi;
                }
            }
        }
        {
            int row = t32 * 32 + 16 + lrow;
            if (row < E) {
                float* orow = out + (size_t)row * H_EDGE;
                #pragma unroll
                for (int t = 0; t < 4; ++t) {
                    bf16x8 wf = *(const bf16x8*)(lds + hbB + tswz(lrow, t * 4 + lk8));
                    bf16x8 ef = EB[t];
                    float4 lo, hi;
                    lo.x = bf2f(wf[0]) + bf2f(ef[0]);
                    lo.y = bf2f(wf[1]) + bf2f(ef[1]);
                    lo.z = bf2f(wf[2]) + bf2f(ef[2]);
                    lo.w = bf2f(wf[3]) + bf2f(ef[3]);
                    hi.x = bf2f(wf[4]) + bf2f(ef[4]);
                    hi.y = bf2f(wf[5]) + bf2f(ef[5]);
                    hi.z = bf2f(wf[6]) + bf2f(ef[6]);
                    hi.w = bf2f(wf[7]) + bf2f(ef[7]);
                    float* dst = orow + t * 32 + lk8 * 8;
                    *(float4*)dst       = lo;
                    *(float4*)(dst + 4) = hi;
                }
            }
        }

        // ---- rotate pipeline state ----
        t32 = nx;  nx = nx2;
        nrA = n2rA; nrB = n2rB;
        nsA = n2sA; ndA = n2dA; nsB = n2sB; ndB = n2dB;
    }
}

extern "C" void kernel_launch(void* const* d_in, const int* in_sizes, int n_in,
                              void* d_out, int out_size, void* d_ws, size_t ws_size,
                              hipStream_t stream) {
    const float* node  = (const float*)d_in[0];
    const float* edgef = (const float*)d_in[1];
    const int*   ei    = (const int*)d_in[2];    // int32 on device
    const float* W1    = (const float*)d_in[3];
    const float* b1    = (const float*)d_in[4];
    const float* W2    = (const float*)d_in[5];
    const float* b2    = (const float*)d_in[6];
    const float* gamma = (const float*)d_in[7];
    const float* beta  = (const float*)d_in[8];
    float* outp = (float*)d_out;
    const int E = in_sizes[2] / 2;   // edge_index is [2, E]

    hipLaunchKernelGGL(edge_update, dim3(GRID), dim3(BLOCK), 0, stream,
                       node, edgef, ei, W1, b1, W2, b2, gamma, beta, outp, E);
}

// Round 8
// 268.352 us; speedup vs baseline: 2.2869x; 2.2869x over previous
//
#include <hip/hip_runtime.h>
#include <hip/hip_bf16.h>

typedef short bf16x8 __attribute__((ext_vector_type(8)));
typedef float f32x4  __attribute__((ext_vector_type(4)));

#define H_NODE 64
#define H_EDGE 128
#define IN_DIM 256
#define WAVES  8
#define BLOCK  512
#define GRID   256
#define LN_EPS 1e-5f

// Static LDS layout (byte offsets), 128 KiB (1 block/CU):
//   [0,      65536): W1^T bf16: addr = col*512 + ((k*2) ^ ((col&7)<<4)),  col in [0,128), k in [0,256)
//   [65536,  98304): W2^T bf16: addr = 65536 + col*256 + ((k*2) ^ ((col&7)<<4)), k in [0,128)
//   [98304, 131072): per-wave transpose tile (16 rows x 128 bf16, 4KB x 8 waves)
//
// Round-8: REVERT to the round-3 champion (262.5us) verbatim -- every structural
// variant since (late stream re-read r4, 12-wave r5, swapped-MFMA r6, row-pair
// r7) regressed, mostly via register spills (WRITE_SIZE tripwire).
// Single bundled change, mechanism-isolated, zero register/data-path impact:
// NON-TEMPORAL cache policy on the pure streams:
//   - edgef prefetch loads  -> __builtin_nontemporal_load  (read-once stream,
//     consumed entirely from registers; retention only pollutes L2)
//   - out stores            -> __builtin_nontemporal_store (write-once stream)
// Node-table loads keep NORMAL policy (only data with reuse; 12.8MB working
// set benefits from whatever L2/L3 residency the streams stop stealing).
// Predicted: FETCH 642->~600MB (fewer node refetches), dur -> ~250us.
// Tripwires: WRITE > 600MB = spills (impossible here); dur > 268us = NT hurts
// -> final revert to pure r3.

static __device__ __forceinline__ short f2bf(float x) {
    __hip_bfloat16 h = __float2bfloat16(x);   // RNE
    return *reinterpret_cast<short*>(&h);
}

static __device__ __forceinline__ float bf2f(short s) {
    union { unsigned int u; float f; } v;
    v.u = ((unsigned int)(unsigned short)s) << 16;
    return v.f;
}

static __device__ __forceinline__ int tswz(int r, int g) {
    return r * 256 + ((g ^ ((r >> 2) << 1)) << 4);
}

static __device__ __forceinline__ bf16x8 cvt8(f32x4 lo, f32x4 hi) {
    bf16x8 f;
    f[0] = f2bf(lo[0]); f[1] = f2bf(lo[1]); f[2] = f2bf(lo[2]); f[3] = f2bf(lo[3]);
    f[4] = f2bf(hi[0]); f[5] = f2bf(hi[1]); f[6] = f2bf(hi[2]); f[7] = f2bf(hi[3]);
    return f;
}

extern "C" __global__ void __launch_bounds__(BLOCK, 2)
edge_update(const float* __restrict__ node,
            const float* __restrict__ edgef,
            const int* __restrict__ ei,          // int32 on device
            const float* __restrict__ W1, const float* __restrict__ b1,
            const float* __restrict__ W2, const float* __restrict__ b2,
            const float* __restrict__ gamma, const float* __restrict__ beta,
            float* __restrict__ out, int E)
{
    __shared__ char lds[131072];
    const int tid = threadIdx.x;

    // ---- stage W1^T (bf16, swizzled) ----
    #pragma unroll 4
    for (int i = 0; i < 64; ++i) {
        int e = tid + i * BLOCK;            // e < 32768; W1 is [k][n], k<256, n<128
        int k = e >> 7, n = e & 127;
        float v = W1[e];
        int addr = n * 512 + ((k * 2) ^ ((n & 7) << 4));
        *(short*)(lds + addr) = f2bf(v);
    }
    // ---- stage W2^T ----
    #pragma unroll 4
    for (int i = 0; i < 32; ++i) {
        int e = tid + i * BLOCK;            // e < 16384; W2 is [k][n], k<128, n<128
        int k = e >> 7, n = e & 127;
        float v = W2[e];
        int addr = 65536 + n * 256 + ((k * 2) ^ ((n & 7) << 4));
        *(short*)(lds + addr) = f2bf(v);
    }
    __syncthreads();

    const int wid   = tid >> 6;
    const int lane  = tid & 63;
    const int lrow  = lane & 15;   // A-frag row / C col / B col
    const int lk8   = lane >> 4;   // k-subchunk 0..3
    const int hbase = 98304 + wid * 4096;

    // per-lane column constants (persistent; plenty of regs at 2 waves/SIMD)
    float bias1[8], bias2[8], g8[8], bt8[8];
    #pragma unroll
    for (int n = 0; n < 8; ++n) {
        int c = n * 16 + lrow;
        bias1[n] = b1[c]; bias2[n] = b2[c]; g8[n] = gamma[c]; bt8[n] = beta[c];
    }

    const int ntiles  = (E + 15) >> 4;
    const int wstride = GRID * WAVES;

    int tile = blockIdx.x * WAVES + wid;
    if (tile >= ntiles) return;

    // ---- prologue: indices + staged gather for tile t; indices for t+1 ----
    int rowg = tile * 16 + lrow; if (rowg >= E) rowg = E - 1;
    int sidx = ei[rowg];
    int didx = ei[E + rowg];

    f32x4 Sn0, Sn1, Sn2, Sn3, Sn4, Sn5, Sn6, Sn7;   // node src/dst raw
    f32x4 Se0, Se1, Se2, Se3, Se4, Se5, Se6, Se7;   // edge row raw
    {
        const float* sp = node + (size_t)sidx * H_NODE + lk8 * 8;
        const float* dp = node + (size_t)didx * H_NODE + lk8 * 8;
        const float* ep = edgef + (size_t)rowg * H_EDGE + lk8 * 8;
        Sn0 = *(const f32x4*)(sp);      Sn1 = *(const f32x4*)(sp + 4);
        Sn2 = *(const f32x4*)(sp + 32); Sn3 = *(const f32x4*)(sp + 36);
        Sn4 = *(const f32x4*)(dp);      Sn5 = *(const f32x4*)(dp + 4);
        Sn6 = *(const f32x4*)(dp + 32); Sn7 = *(const f32x4*)(dp + 36);
        Se0 = __builtin_nontemporal_load((const f32x4*)(ep));
        Se1 = __builtin_nontemporal_load((const f32x4*)(ep + 4));
        Se2 = __builtin_nontemporal_load((const f32x4*)(ep + 32));
        Se3 = __builtin_nontemporal_load((const f32x4*)(ep + 36));
        Se4 = __builtin_nontemporal_load((const f32x4*)(ep + 64));
        Se5 = __builtin_nontemporal_load((const f32x4*)(ep + 68));
        Se6 = __builtin_nontemporal_load((const f32x4*)(ep + 96));
        Se7 = __builtin_nontemporal_load((const f32x4*)(ep + 100));
    }
    int next  = tile + wstride;
    int nrowg = next * 16 + lrow; if (nrowg >= E) nrowg = E - 1;
    int nsidx = ei[nrowg];
    int ndidx = ei[E + nrowg];

    while (tile < ntiles) {
        // ---- fold staged gather (issued one full tile ago) into A1 ----
        bf16x8 A1[8];
        A1[0] = cvt8(Sn0, Sn1);
        A1[1] = cvt8(Sn2, Sn3);
        A1[2] = cvt8(Sn4, Sn5);
        A1[3] = cvt8(Sn6, Sn7);
        A1[4] = cvt8(Se0, Se1);
        A1[5] = cvt8(Se2, Se3);
        A1[6] = cvt8(Se4, Se5);
        A1[7] = cvt8(Se6, Se7);

        // ---- issue NEXT tile's FULL gather burst (in flight all tile) ----
        {
            const float* sp = node + (size_t)nsidx * H_NODE + lk8 * 8;
            const float* dp = node + (size_t)ndidx * H_NODE + lk8 * 8;
            const float* ep = edgef + (size_t)nrowg * H_EDGE + lk8 * 8;
            Sn0 = *(const f32x4*)(sp);      Sn1 = *(const f32x4*)(sp + 4);
            Sn2 = *(const f32x4*)(sp + 32); Sn3 = *(const f32x4*)(sp + 36);
            Sn4 = *(const f32x4*)(dp);      Sn5 = *(const f32x4*)(dp + 4);
            Sn6 = *(const f32x4*)(dp + 32); Sn7 = *(const f32x4*)(dp + 36);
            Se0 = __builtin_nontemporal_load((const f32x4*)(ep));
            Se1 = __builtin_nontemporal_load((const f32x4*)(ep + 4));
            Se2 = __builtin_nontemporal_load((const f32x4*)(ep + 32));
            Se3 = __builtin_nontemporal_load((const f32x4*)(ep + 36));
            Se4 = __builtin_nontemporal_load((const f32x4*)(ep + 64));
            Se5 = __builtin_nontemporal_load((const f32x4*)(ep + 68));
            Se6 = __builtin_nontemporal_load((const f32x4*)(ep + 96));
            Se7 = __builtin_nontemporal_load((const f32x4*)(ep + 100));
        }
        // ---- prefetch tile+2 indices ----
        int t2 = next + wstride;
        int t2rowg = t2 * 16 + lrow; if (t2rowg >= E) t2rowg = E - 1;
        int t2s = ei[t2rowg];
        int t2d = ei[E + t2rowg];

        // ---- GEMM1: [16x256] @ [256x128] ----
        f32x4 acc[8];
        #pragma unroll
        for (int n = 0; n < 8; ++n) acc[n] = (f32x4){0.f, 0.f, 0.f, 0.f};
        #pragma unroll
        for (int n = 0; n < 8; ++n) {
            const int col = n * 16 + lrow;
            const int cb  = col * 512;
            const int sw  = (col & 7) << 4;
            #pragma unroll
            for (int t = 0; t < 8; ++t) {
                int kb = t * 64 + lk8 * 16;
                bf16x8 bfrag = *(const bf16x8*)(lds + cb + (kb ^ sw));
                acc[n] = __builtin_amdgcn_mfma_f32_16x16x32_bf16(A1[t], bfrag, acc[n], 0, 0, 0);
            }
        }

        // ---- bias + relu -> h (bf16) to per-wave LDS (conflict-free swizzle) ----
        #pragma unroll
        for (int n = 0; n < 8; ++n) {
            const int g = n * 2 + (lrow >> 3);
            const int cl = (lrow & 7) * 2;
            #pragma unroll
            for (int i = 0; i < 4; ++i) {
                float u = fmaxf(acc[n][i] + bias1[n], 0.f);
                int row = lk8 * 4 + i;
                *(short*)(lds + hbase + tswz(row, g) + cl) = f2bf(u);
            }
        }
        // same-wave cross-lane LDS visibility: drain ds_writes before reads
        asm volatile("s_waitcnt lgkmcnt(0)" ::: "memory");

        // ---- GEMM2: [16x128] @ [128x128] ----
        bf16x8 A2[4];
        #pragma unroll
        for (int t = 0; t < 4; ++t)
            A2[t] = *(const bf16x8*)(lds + hbase + tswz(lrow, t * 4 + lk8));

        f32x4 acc2[8];
        #pragma unroll
        for (int n = 0; n < 8; ++n) acc2[n] = (f32x4){0.f, 0.f, 0.f, 0.f};
        #pragma unroll
        for (int n = 0; n < 8; ++n) {
            const int col = n * 16 + lrow;
            const int cb  = 65536 + col * 256;
            const int sw  = (col & 7) << 4;
            #pragma unroll
            for (int t = 0; t < 4; ++t) {
                int kb = t * 64 + lk8 * 16;
                bf16x8 bfrag = *(const bf16x8*)(lds + cb + (kb ^ sw));
                acc2[n] = __builtin_amdgcn_mfma_f32_16x16x32_bf16(A2[t], bfrag, acc2[n], 0, 0, 0);
            }
        }

        // ---- bias2 + LayerNorm (C-layout) -> w (bf16) back through LDS ----
        #pragma unroll
        for (int i = 0; i < 4; ++i) {
            float u[8];
            float s = 0.f, sq = 0.f;
            #pragma unroll
            for (int n = 0; n < 8; ++n) {
                u[n] = acc2[n][i] + bias2[n];
                s  += u[n];
                sq += u[n] * u[n];
            }
            #pragma unroll
            for (int m = 1; m < 16; m <<= 1) {
                s  += __shfl_xor(s,  m, 64);
                sq += __shfl_xor(sq, m, 64);
            }
            float mu  = s * (1.f / 128.f);
            float var = sq * (1.f / 128.f) - mu * mu;
            float rs  = rsqrtf(var + LN_EPS);
            int row = lk8 * 4 + i;
            const int cl = (lrow & 7) * 2;
            #pragma unroll
            for (int n = 0; n < 8; ++n) {
                float w = (u[n] - mu) * rs * g8[n] + bt8[n];
                *(short*)(lds + hbase + tswz(row, n * 2 + (lrow >> 3)) + cl) = f2bf(w);
            }
        }
        asm volatile("s_waitcnt lgkmcnt(0)" ::: "memory");

        // ---- read w in A-layout, residual from registers, coalesced NT store ----
        {
            int row = tile * 16 + lrow;
            if (row < E) {
                float* orow = out + (size_t)row * H_EDGE;
                #pragma unroll
                for (int t = 0; t < 4; ++t) {
                    bf16x8 wf = *(const bf16x8*)(lds + hbase + tswz(lrow, t * 4 + lk8));
                    bf16x8 ef = A1[t + 4];
                    f32x4 lo, hi;
                    lo[0] = bf2f(wf[0]) + bf2f(ef[0]);
                    lo[1] = bf2f(wf[1]) + bf2f(ef[1]);
                    lo[2] = bf2f(wf[2]) + bf2f(ef[2]);
                    lo[3] = bf2f(wf[3]) + bf2f(ef[3]);
                    hi[0] = bf2f(wf[4]) + bf2f(ef[4]);
                    hi[1] = bf2f(wf[5]) + bf2f(ef[5]);
                    hi[2] = bf2f(wf[6]) + bf2f(ef[6]);
                    hi[3] = bf2f(wf[7]) + bf2f(ef[7]);
                    float* dst = orow + t * 32 + lk8 * 8;
                    __builtin_nontemporal_store(lo, (f32x4*)dst);
                    __builtin_nontemporal_store(hi, (f32x4*)(dst + 4));
                }
            }
        }

        // ---- rotate pipeline state ----
        tile = next;  next = t2;
        nrowg = t2rowg; nsidx = t2s; ndidx = t2d;
    }
}

extern "C" void kernel_launch(void* const* d_in, const int* in_sizes, int n_in,
                              void* d_out, int out_size, void* d_ws, size_t ws_size,
                              hipStream_t stream) {
    const float* node  = (const float*)d_in[0];
    const float* edgef = (const float*)d_in[1];
    const int*   ei    = (const int*)d_in[2];    // int32 on device
    const float* W1    = (const float*)d_in[3];
    const float* b1    = (const float*)d_in[4];
    const float* W2    = (const float*)d_in[5];
    const float* b2    = (const float*)d_in[6];
    const float* gamma = (const float*)d_in[7];
    const float* beta  = (const float*)d_in[8];
    float* outp = (float*)d_out;
    const int E = in_sizes[2] / 2;   // edge_index is [2, E]

    hipLaunchKernelGGL(edge_update, dim3(GRID), dim3(BLOCK), 0, stream,
                       node, edgef, ei, W1, b1, W2, b2, gamma, beta, outp, E);
}

// Round 9
// 261.480 us; speedup vs baseline: 2.3470x; 1.0263x over previous
//
#include <hip/hip_runtime.h>
#include <hip/hip_bf16.h>

typedef short bf16x8 __attribute__((ext_vector_type(8)));
typedef float f32x4  __attribute__((ext_vector_type(4)));

#define H_NODE 64
#define H_EDGE 128
#define IN_DIM 256
#define WAVES  8
#define BLOCK  512
#define GRID   256
#define LN_EPS 1e-5f

// Static LDS layout (byte offsets), 128 KiB (1 block/CU):
//   [0,      65536): W1^T bf16: addr = col*512 + ((k*2) ^ ((col&7)<<4)),  col in [0,128), k in [0,256)
//   [65536,  98304): W2^T bf16: addr = 65536 + col*256 + ((k*2) ^ ((col&7)<<4)), k in [0,128)
//   [98304, 131072): per-wave transpose tile (16 rows x 128 bf16, 4KB x 8 waves)
//
// Round-9: r3 champion (262.5us) + NON-TEMPORAL STORES ONLY (unbundled from r8).
// r8's counters isolated the mechanism: NT out-stores eliminate write-allocate
// RMW (FETCH 642->440 MB, -202 MB of HBM fetches of soon-overwritten lines).
// r8's NT *loads* on edgef are reverted: they deny L2/L3 allocation to the
// edge stream and were the likely source of r8's small regression (268 vs 262).
// Everything else (8 waves x 256 VGPR, full 1-tile-deep register staging,
// h/w LDS transpose, register-resident residual) is r3-verbatim.
// Signature to confirm mechanism: FETCH ~440-480 MB with normal loads.
// Decision rule: dur >= 262us -> structure is at its practical ceiling;
// final answer = faster of {r3, this}.

static __device__ __forceinline__ short f2bf(float x) {
    __hip_bfloat16 h = __float2bfloat16(x);   // RNE
    return *reinterpret_cast<short*>(&h);
}

static __device__ __forceinline__ float bf2f(short s) {
    union { unsigned int u; float f; } v;
    v.u = ((unsigned int)(unsigned short)s) << 16;
    return v.f;
}

static __device__ __forceinline__ int tswz(int r, int g) {
    return r * 256 + ((g ^ ((r >> 2) << 1)) << 4);
}

static __device__ __forceinline__ bf16x8 cvt8(f32x4 lo, f32x4 hi) {
    bf16x8 f;
    f[0] = f2bf(lo[0]); f[1] = f2bf(lo[1]); f[2] = f2bf(lo[2]); f[3] = f2bf(lo[3]);
    f[4] = f2bf(hi[0]); f[5] = f2bf(hi[1]); f[6] = f2bf(hi[2]); f[7] = f2bf(hi[3]);
    return f;
}

extern "C" __global__ void __launch_bounds__(BLOCK, 2)
edge_update(const float* __restrict__ node,
            const float* __restrict__ edgef,
            const int* __restrict__ ei,          // int32 on device
            const float* __restrict__ W1, const float* __restrict__ b1,
            const float* __restrict__ W2, const float* __restrict__ b2,
            const float* __restrict__ gamma, const float* __restrict__ beta,
            float* __restrict__ out, int E)
{
    __shared__ char lds[131072];
    const int tid = threadIdx.x;

    // ---- stage W1^T (bf16, swizzled) ----
    #pragma unroll 4
    for (int i = 0; i < 64; ++i) {
        int e = tid + i * BLOCK;            // e < 32768; W1 is [k][n], k<256, n<128
        int k = e >> 7, n = e & 127;
        float v = W1[e];
        int addr = n * 512 + ((k * 2) ^ ((n & 7) << 4));
        *(short*)(lds + addr) = f2bf(v);
    }
    // ---- stage W2^T ----
    #pragma unroll 4
    for (int i = 0; i < 32; ++i) {
        int e = tid + i * BLOCK;            // e < 16384; W2 is [k][n], k<128, n<128
        int k = e >> 7, n = e & 127;
        float v = W2[e];
        int addr = 65536 + n * 256 + ((k * 2) ^ ((n & 7) << 4));
        *(short*)(lds + addr) = f2bf(v);
    }
    __syncthreads();

    const int wid   = tid >> 6;
    const int lane  = tid & 63;
    const int lrow  = lane & 15;   // A-frag row / C col / B col
    const int lk8   = lane >> 4;   // k-subchunk 0..3
    const int hbase = 98304 + wid * 4096;

    // per-lane column constants (persistent; plenty of regs at 2 waves/SIMD)
    float bias1[8], bias2[8], g8[8], bt8[8];
    #pragma unroll
    for (int n = 0; n < 8; ++n) {
        int c = n * 16 + lrow;
        bias1[n] = b1[c]; bias2[n] = b2[c]; g8[n] = gamma[c]; bt8[n] = beta[c];
    }

    const int ntiles  = (E + 15) >> 4;
    const int wstride = GRID * WAVES;

    int tile = blockIdx.x * WAVES + wid;
    if (tile >= ntiles) return;

    // ---- prologue: indices + staged gather for tile t; indices for t+1 ----
    int rowg = tile * 16 + lrow; if (rowg >= E) rowg = E - 1;
    int sidx = ei[rowg];
    int didx = ei[E + rowg];

    f32x4 Sn0, Sn1, Sn2, Sn3, Sn4, Sn5, Sn6, Sn7;   // node src/dst raw
    f32x4 Se0, Se1, Se2, Se3, Se4, Se5, Se6, Se7;   // edge row raw
    {
        const float* sp = node + (size_t)sidx * H_NODE + lk8 * 8;
        const float* dp = node + (size_t)didx * H_NODE + lk8 * 8;
        const float* ep = edgef + (size_t)rowg * H_EDGE + lk8 * 8;
        Sn0 = *(const f32x4*)(sp);      Sn1 = *(const f32x4*)(sp + 4);
        Sn2 = *(const f32x4*)(sp + 32); Sn3 = *(const f32x4*)(sp + 36);
        Sn4 = *(const f32x4*)(dp);      Sn5 = *(const f32x4*)(dp + 4);
        Sn6 = *(const f32x4*)(dp + 32); Sn7 = *(const f32x4*)(dp + 36);
        Se0 = *(const f32x4*)(ep);      Se1 = *(const f32x4*)(ep + 4);
        Se2 = *(const f32x4*)(ep + 32); Se3 = *(const f32x4*)(ep + 36);
        Se4 = *(const f32x4*)(ep + 64); Se5 = *(const f32x4*)(ep + 68);
        Se6 = *(const f32x4*)(ep + 96); Se7 = *(const f32x4*)(ep + 100);
    }
    int next  = tile + wstride;
    int nrowg = next * 16 + lrow; if (nrowg >= E) nrowg = E - 1;
    int nsidx = ei[nrowg];
    int ndidx = ei[E + nrowg];

    while (tile < ntiles) {
        // ---- fold staged gather (issued one full tile ago) into A1 ----
        bf16x8 A1[8];
        A1[0] = cvt8(Sn0, Sn1);
        A1[1] = cvt8(Sn2, Sn3);
        A1[2] = cvt8(Sn4, Sn5);
        A1[3] = cvt8(Sn6, Sn7);
        A1[4] = cvt8(Se0, Se1);
        A1[5] = cvt8(Se2, Se3);
        A1[6] = cvt8(Se4, Se5);
        A1[7] = cvt8(Se6, Se7);

        // ---- issue NEXT tile's FULL gather burst (in flight all tile) ----
        {
            const float* sp = node + (size_t)nsidx * H_NODE + lk8 * 8;
            const float* dp = node + (size_t)ndidx * H_NODE + lk8 * 8;
            const float* ep = edgef + (size_t)nrowg * H_EDGE + lk8 * 8;
            Sn0 = *(const f32x4*)(sp);      Sn1 = *(const f32x4*)(sp + 4);
            Sn2 = *(const f32x4*)(sp + 32); Sn3 = *(const f32x4*)(sp + 36);
            Sn4 = *(const f32x4*)(dp);      Sn5 = *(const f32x4*)(dp + 4);
            Sn6 = *(const f32x4*)(dp + 32); Sn7 = *(const f32x4*)(dp + 36);
            Se0 = *(const f32x4*)(ep);      Se1 = *(const f32x4*)(ep + 4);
            Se2 = *(const f32x4*)(ep + 32); Se3 = *(const f32x4*)(ep + 36);
            Se4 = *(const f32x4*)(ep + 64); Se5 = *(const f32x4*)(ep + 68);
            Se6 = *(const f32x4*)(ep + 96); Se7 = *(const f32x4*)(ep + 100);
        }
        // ---- prefetch tile+2 indices ----
        int t2 = next + wstride;
        int t2rowg = t2 * 16 + lrow; if (t2rowg >= E) t2rowg = E - 1;
        int t2s = ei[t2rowg];
        int t2d = ei[E + t2rowg];

        // ---- GEMM1: [16x256] @ [256x128] ----
        f32x4 acc[8];
        #pragma unroll
        for (int n = 0; n < 8; ++n) acc[n] = (f32x4){0.f, 0.f, 0.f, 0.f};
        #pragma unroll
        for (int n = 0; n < 8; ++n) {
            const int col = n * 16 + lrow;
            const int cb  = col * 512;
            const int sw  = (col & 7) << 4;
            #pragma unroll
            for (int t = 0; t < 8; ++t) {
                int kb = t * 64 + lk8 * 16;
                bf16x8 bfrag = *(const bf16x8*)(lds + cb + (kb ^ sw));
                acc[n] = __builtin_amdgcn_mfma_f32_16x16x32_bf16(A1[t], bfrag, acc[n], 0, 0, 0);
            }
        }

        // ---- bias + relu -> h (bf16) to per-wave LDS (conflict-free swizzle) ----
        #pragma unroll
        for (int n = 0; n < 8; ++n) {
            const int g = n * 2 + (lrow >> 3);
            const int cl = (lrow & 7) * 2;
            #pragma unroll
            for (int i = 0; i < 4; ++i) {
                float u = fmaxf(acc[n][i] + bias1[n], 0.f);
                int row = lk8 * 4 + i;
                *(short*)(lds + hbase + tswz(row, g) + cl) = f2bf(u);
            }
        }
        // same-wave cross-lane LDS visibility: drain ds_writes before reads
        asm volatile("s_waitcnt lgkmcnt(0)" ::: "memory");

        // ---- GEMM2: [16x128] @ [128x128] ----
        bf16x8 A2[4];
        #pragma unroll
        for (int t = 0; t < 4; ++t)
            A2[t] = *(const bf16x8*)(lds + hbase + tswz(lrow, t * 4 + lk8));

        f32x4 acc2[8];
        #pragma unroll
        for (int n = 0; n < 8; ++n) acc2[n] = (f32x4){0.f, 0.f, 0.f, 0.f};
        #pragma unroll
        for (int n = 0; n < 8; ++n) {
            const int col = n * 16 + lrow;
            const int cb  = 65536 + col * 256;
            const int sw  = (col & 7) << 4;
            #pragma unroll
            for (int t = 0; t < 4; ++t) {
                int kb = t * 64 + lk8 * 16;
                bf16x8 bfrag = *(const bf16x8*)(lds + cb + (kb ^ sw));
                acc2[n] = __builtin_amdgcn_mfma_f32_16x16x32_bf16(A2[t], bfrag, acc2[n], 0, 0, 0);
            }
        }

        // ---- bias2 + LayerNorm (C-layout) -> w (bf16) back through LDS ----
        #pragma unroll
        for (int i = 0; i < 4; ++i) {
            float u[8];
            float s = 0.f, sq = 0.f;
            #pragma unroll
            for (int n = 0; n < 8; ++n) {
                u[n] = acc2[n][i] + bias2[n];
                s  += u[n];
                sq += u[n] * u[n];
            }
            #pragma unroll
            for (int m = 1; m < 16; m <<= 1) {
                s  += __shfl_xor(s,  m, 64);
                sq += __shfl_xor(sq, m, 64);
            }
            float mu  = s * (1.f / 128.f);
            float var = sq * (1.f / 128.f) - mu * mu;
            float rs  = rsqrtf(var + LN_EPS);
            int row = lk8 * 4 + i;
            const int cl = (lrow & 7) * 2;
            #pragma unroll
            for (int n = 0; n < 8; ++n) {
                float w = (u[n] - mu) * rs * g8[n] + bt8[n];
                *(short*)(lds + hbase + tswz(row, n * 2 + (lrow >> 3)) + cl) = f2bf(w);
            }
        }
        asm volatile("s_waitcnt lgkmcnt(0)" ::: "memory");

        // ---- read w in A-layout, residual from registers, coalesced NT store ----
        {
            int row = tile * 16 + lrow;
            if (row < E) {
                float* orow = out + (size_t)row * H_EDGE;
                #pragma unroll
                for (int t = 0; t < 4; ++t) {
                    bf16x8 wf = *(const bf16x8*)(lds + hbase + tswz(lrow, t * 4 + lk8));
                    bf16x8 ef = A1[t + 4];
                    f32x4 lo, hi;
                    lo[0] = bf2f(wf[0]) + bf2f(ef[0]);
                    lo[1] = bf2f(wf[1]) + bf2f(ef[1]);
                    lo[2] = bf2f(wf[2]) + bf2f(ef[2]);
                    lo[3] = bf2f(wf[3]) + bf2f(ef[3]);
                    hi[0] = bf2f(wf[4]) + bf2f(ef[4]);
                    hi[1] = bf2f(wf[5]) + bf2f(ef[5]);
                    hi[2] = bf2f(wf[6]) + bf2f(ef[6]);
                    hi[3] = bf2f(wf[7]) + bf2f(ef[7]);
                    float* dst = orow + t * 32 + lk8 * 8;
                    __builtin_nontemporal_store(lo, (f32x4*)dst);
                    __builtin_nontemporal_store(hi, (f32x4*)(dst + 4));
                }
            }
        }

        // ---- rotate pipeline state ----
        tile = next;  next = t2;
        nrowg = t2rowg; nsidx = t2s; ndidx = t2d;
    }
}

extern "C" void kernel_launch(void* const* d_in, const int* in_sizes, int n_in,
                              void* d_out, int out_size, void* d_ws, size_t ws_size,
                              hipStream_t stream) {
    const float* node  = (const float*)d_in[0];
    const float* edgef = (const float*)d_in[1];
    const int*   ei    = (const int*)d_in[2];    // int32 on device
    const float* W1    = (const float*)d_in[3];
    const float* b1    = (const float*)d_in[4];
    const float* W2    = (const float*)d_in[5];
    const float* b2    = (const float*)d_in[6];
    const float* gamma = (const float*)d_in[7];
    const float* beta  = (const float*)d_in[8];
    float* outp = (float*)d_out;
    const int E = in_sizes[2] / 2;   // edge_index is [2, E]

    hipLaunchKernelGGL(edge_update, dim3(GRID), dim3(BLOCK), 0, stream,
                       node, edgef, ei, W1, b1, W2, b2, gamma, beta, outp, E);
}